// Round 4
// baseline (287.187 us; speedup 1.0000x reference)
//
#include <hip/hip_runtime.h>
#include <math.h>

// Problem constants (match reference)
constexpr int N_ROWS = 100000;   // outputSize
constexpr int D      = 128;      // feature dim
constexpr int B      = 128;      // batch
constexpr int KP1    = 4097;     // K+1
constexpr int TOTAL_PAIRS = B * KP1;            // 524,416
constexpr float INV_T = 1.0f / 0.07f;
constexpr int N4 = N_ROWS * (D / 4);            // float4 per bank: 3.2M

constexpr int SC_BLOCKS = 2048;  // score blocks: 16 chunks per b (all co-resident)
constexpr int CP_BLOCKS = 2048;  // copy blocks

// Row-range phasing: gathers restricted to 12.5k-row windows (12.8 MB both
// banks) so re-referenced rows stay L3-resident. Round-3 counters showed the
// full 102 MB working set misses ~35% of re-refs (FETCH 254 MB vs 104
// compulsory) -> effective L3 capacity for this stream is ~100-130 MB.
constexpr int NRANGE = 8;
constexpr int RSPAN  = N_ROWS / NRANGE;         // 12500

typedef float fvec4 __attribute__((ext_vector_type(4)));  // nontemporal-store-safe

// ---------------------------------------------------------------------------
__global__ void init_ws_kernel(float* ws) {
    if (threadIdx.x < 2) ws[threadIdx.x] = 0.0f;
}

__device__ __forceinline__ float dot4(float4 a, float4 b) {
    return a.x * b.x + a.y * b.y + a.z * b.z + a.w * b.w;
}

// xor-butterfly over the 32-lane group: leaves the full sum in ALL lanes
__device__ __forceinline__ float red32(float v) {
    #pragma unroll
    for (int off = 16; off >= 1; off >>= 1) v += __shfl_xor(v, off);
    return v;
}

// ---------------------------------------------------------------------------
// Phase 1: score. 16 blocks per b, each owns a 256-wide k chunk; each 32-lane
// group owns 32 k's (one row index per lane, kept in register). The group
// loops over NRANGE row-windows; per window it ballots which of its 32 pairs
// are in-window (group-uniform mask) and processes them 2-deep pipelined
// (4 row-gathers in flight). exp results buffered in LDS, stored coalesced
// at the end; block Z-sum from the same LDS pass.
__global__ __launch_bounds__(256) void score_kernel(
    const float* __restrict__ v1, const float* __restrict__ v2,
    const int* __restrict__ idx,
    const float* __restrict__ mem1, const float* __restrict__ mem2,
    float* __restrict__ out,          // [0:T) unnorm out_v1, [T:2T) unnorm out_v2
    float* __restrict__ sums)         // ws: 2 floats
{
    __shared__ float s_e1[260], s_e2[260];
    __shared__ float s_p1[4], s_p2[4];

    const int sid   = blockIdx.x;                     // 0..2047
    const int tid   = threadIdx.x;
    const int l     = tid & 31;                       // lane in 32-lane group
    const int grp   = tid >> 5;                       // 0..7
    const int b     = sid >> 4;                       // 16 blocks per b
    const int chunk = sid & 15;                       // which 256-wide k chunk
    const int cnt   = (chunk == 15) ? 257 : 256;      // chunk 15 also owns k=4096
    const int ibase = b * KP1 + chunk * 256;
    const int lk    = grp * 32;                       // group's local k offset

    const float4* __restrict__ m1 = (const float4*)mem1;
    const float4* __restrict__ m2 = (const float4*)mem2;
    const float4 a1 = ((const float4*)v1)[b * 32 + l];
    const float4 a2 = ((const float4*)v2)[b * 32 + l];

    // lane l owns pair (local k = lk + l); its bank row stays in a register
    const int  row_l    = idx[ibase + lk + l];
    const bool has_tail = (chunk == 15) && (grp == 7);
    const int  row_t    = has_tail ? idx[b * KP1 + 4096] : 0;

    for (int r = 0; r < NRANGE; ++r) {
        const int lo = r * RSPAN;
        const int hi = lo + RSPAN;

        unsigned long long bal = __ballot(row_l >= lo && row_l < hi);
        unsigned mask = (tid & 32) ? (unsigned)(bal >> 32) : (unsigned)bal;

        while (mask) {
            int j0 = __builtin_ctz(mask); mask &= mask - 1;
            int r0 = __shfl(row_l, j0, 32);
            float4 wA0 = m2[(size_t)r0 * 32 + l];     // out_v1 = mem2 . v1
            float4 wB0 = m1[(size_t)r0 * 32 + l];     // out_v2 = mem1 . v2

            int j1 = -1;
            float4 wA1{}, wB1{};
            if (mask) {
                j1 = __builtin_ctz(mask); mask &= mask - 1;
                int r1 = __shfl(row_l, j1, 32);
                wA1 = m2[(size_t)r1 * 32 + l];
                wB1 = m1[(size_t)r1 * 32 + l];
            }

            float eA0 = __expf(red32(dot4(wA0, a1)) * INV_T);
            float eB0 = __expf(red32(dot4(wB0, a2)) * INV_T);
            if (l == 0) { s_e1[lk + j0] = eA0; s_e2[lk + j0] = eB0; }

            if (j1 >= 0) {
                float eA1 = __expf(red32(dot4(wA1, a1)) * INV_T);
                float eB1 = __expf(red32(dot4(wB1, a2)) * INV_T);
                if (l == 0) { s_e1[lk + j1] = eA1; s_e2[lk + j1] = eB1; }
            }
        }

        if (has_tail && row_t >= lo && row_t < hi) {
            float4 wA = m2[(size_t)row_t * 32 + l];
            float4 wB = m1[(size_t)row_t * 32 + l];
            float eA = __expf(red32(dot4(wA, a1)) * INV_T);
            float eB = __expf(red32(dot4(wB, a2)) * INV_T);
            if (l == 0) { s_e1[256] = eA; s_e2[256] = eB; }
        }
    }
    __syncthreads();

    // coalesced store of the block's 256(+1) scores + Z partial sums
    float p1 = 0.0f, p2 = 0.0f;
    for (int t = tid; t < cnt; t += 256) {
        float e1 = s_e1[t], e2 = s_e2[t];
        out[ibase + t]               = e1;
        out[TOTAL_PAIRS + ibase + t] = e2;
        p1 += e1; p2 += e2;
    }
    #pragma unroll
    for (int off = 32; off >= 1; off >>= 1) {
        p1 += __shfl_xor(p1, off);
        p2 += __shfl_xor(p2, off);
    }
    int w = tid >> 6;
    if ((tid & 63) == 0) { s_p1[w] = p1; s_p2[w] = p2; }
    __syncthreads();
    if (tid == 0) {
        float t1 = s_p1[0] + s_p1[1] + s_p1[2] + s_p1[3];
        float t2 = s_p2[0] + s_p2[1] + s_p2[2] + s_p2[3];
        atomicAdd(&sums[0], t1);
        atomicAdd(&sums[1], t2);
    }
}

// ---------------------------------------------------------------------------
// Phase 2: pure-stream copy of both banks + scale the score regions by 1/Z
// (sums are final: kernel-boundary ordering on the stream).
__global__ __launch_bounds__(256) void copy_scale_kernel(
    const float* __restrict__ mem1, const float* __restrict__ mem2,
    float* __restrict__ o1, float* __restrict__ o2,
    float* __restrict__ out, const float* __restrict__ sums)
{
    const fvec4* __restrict__ m1 = (const fvec4*)mem1;
    const fvec4* __restrict__ m2 = (const fvec4*)mem2;
    fvec4* __restrict__ d1 = (fvec4*)o1;
    fvec4* __restrict__ d2 = (fvec4*)o2;

    int tid    = blockIdx.x * 256 + threadIdx.x;
    int stride = CP_BLOCKS * 256;
    for (int i = tid; i < N4; i += stride) {
        fvec4 x1 = m1[i];
        fvec4 x2 = m2[i];
        __builtin_nontemporal_store(x1, &d1[i]);
        __builtin_nontemporal_store(x2, &d2[i]);
    }

    float sc1 = (float)((double)TOTAL_PAIRS / ((double)sums[0] * (double)N_ROWS));
    float sc2 = (float)((double)TOTAL_PAIRS / ((double)sums[1] * (double)N_ROWS));
    for (int i = tid; i < 2 * TOTAL_PAIRS; i += stride) {
        out[i] *= (i < TOTAL_PAIRS) ? sc1 : sc2;
    }
}

// ---------------------------------------------------------------------------
// Phase 3: overwrite the y-rows of the copied banks with
// normalize(0.5*mem + 0.5*v). Must run after the copy (stream-ordered).
__global__ void rowupd_kernel(
    const float* __restrict__ v1, const float* __restrict__ v2,
    const int* __restrict__ y,
    const float* __restrict__ mem1, const float* __restrict__ mem2,
    float* __restrict__ o1, float* __restrict__ o2)
{
    int b    = blockIdx.x & (B - 1);
    int bank = blockIdx.x >> 7;
    int lane = threadIdx.x;
    const float2* __restrict__ m = (const float2*)(bank ? mem2 : mem1);
    const float2* __restrict__ v = (const float2*)(bank ? v2 : v1);
    float2* __restrict__ o       = (float2*)(bank ? o2 : o1);
    int row = y[b];
    float2 mv = m[(size_t)row * 64 + lane];
    float2 vv = v[b * 64 + lane];
    float2 u;
    u.x = 0.5f * mv.x + 0.5f * vv.x;
    u.y = 0.5f * mv.y + 0.5f * vv.y;
    float ss = u.x * u.x + u.y * u.y;
    #pragma unroll
    for (int off = 32; off >= 1; off >>= 1) ss += __shfl_xor(ss, off);
    float inv = 1.0f / sqrtf(ss);
    float2 r; r.x = u.x * inv; r.y = u.y * inv;
    o[(size_t)row * 64 + lane] = r;
}

// ---------------------------------------------------------------------------
extern "C" void kernel_launch(void* const* d_in, const int* in_sizes, int n_in,
                              void* d_out, int out_size, void* d_ws, size_t ws_size,
                              hipStream_t stream) {
    const float* v1   = (const float*)d_in[0];
    const float* v2   = (const float*)d_in[1];
    const int*   idx  = (const int*)d_in[2];
    const int*   y    = (const int*)d_in[3];
    const float* mem1 = (const float*)d_in[4];
    const float* mem2 = (const float*)d_in[5];

    float* out = (float*)d_out;
    float* out_mem1 = out + 2 * (size_t)TOTAL_PAIRS;
    float* out_mem2 = out_mem1 + (size_t)N_ROWS * D;
    float* sums = (float*)d_ws;

    init_ws_kernel<<<1, 64, 0, stream>>>(sums);

    score_kernel<<<SC_BLOCKS, 256, 0, stream>>>(
        v1, v2, idx, mem1, mem2, out, sums);

    copy_scale_kernel<<<CP_BLOCKS, 256, 0, stream>>>(
        mem1, mem2, out_mem1, out_mem2, out, sums);

    rowupd_kernel<<<2 * B, 64, 0, stream>>>(
        v1, v2, y, mem1, mem2, out_mem1, out_mem2);
}